// Round 10
// baseline (597.616 us; speedup 1.0000x reference)
//
#include <hip/hip_runtime.h>
#include <math.h>

#define BATCH 4
#define SEQ   2048
#define HDIM  256
#define GAMMA 0.9f
#define WMAX  256   // gamma^255 ~ 2e-12: banded causal window
#define QB    16    // q-rows per attn block
#define MB    16    // m-rows per chunk

typedef unsigned short ushort8 __attribute__((ext_vector_type(8)));

// float -> bf16 bits, round-to-nearest-even
__device__ __forceinline__ unsigned short f2bf(float f) {
    union { float f; unsigned int u; } v; v.f = f;
    unsigned int u = v.u;
    u += 0x7FFFu + ((u >> 16) & 1u);
    return (unsigned short)(u >> 16);
}

// ---------------------------------------------------------------------------
// Kernel 1: projections + rotation, fp32 to workspace. (byte-identical to R6)
// grid = (B*S, 3); block = 256 threads (one per output column).
// ---------------------------------------------------------------------------
__global__ __launch_bounds__(256)
void proj_kernel(const float* __restrict__ X,
                 const float* __restrict__ WQ,
                 const float* __restrict__ WK,
                 const float* __restrict__ WV,
                 const float* __restrict__ theta,
                 float* __restrict__ Qc, float* __restrict__ Qs,
                 float* __restrict__ Kc, float* __restrict__ Ks,
                 float* __restrict__ Vv)
{
    __shared__ float sX[HDIM];
    const int row = blockIdx.x;              // 0 .. B*S-1
    const int sec = blockIdx.y;              // 0,1,2
    const int h   = threadIdx.x;             // 0 .. 255
    const float* W = (sec == 0) ? WQ : (sec == 1) ? WK : WV;

    sX[h] = X[(size_t)row * HDIM + h];
    __syncthreads();

    float acc = 0.f;
    #pragma unroll 8
    for (int k = 0; k < HDIM; ++k)
        acc += sX[k] * W[(size_t)k * HDIM + h];   // W[k][h], coalesced over h

    const size_t o = (size_t)row * HDIM + h;
    if (sec == 2) {
        Vv[o] = acc;
    } else {
        const int s = row & (SEQ - 1);            // position within batch
        float sn, cs;
        sincosf((float)(s + 1) * theta[h], &sn, &cs);
        if (sec == 0) { Qc[o] = acc * cs; Qs[o] = acc * sn; }
        else          { Kc[o] = acc * cs; Ks[o] = acc * sn; }
    }
}

// ---------------------------------------------------------------------------
// Kernel 2: banded complex attention (values identical to R6).
// EPILOGUE CHANGE ONLY: each element's bf16 pair written as [im, re].
// Rationale: sigma_im ~ 0.02*sigma_re (theta tiny), so R6's error
// 0.0692 = max|ref_re| is the exact signature of full-scale values at the
// wrong slot of the pair; R8's 0.0957 = sqrt2-decorrelated confirms values
// are full-scale and h-correct.
// ---------------------------------------------------------------------------
__global__ __launch_bounds__(256)
void attn_kernel(const float* __restrict__ Qc, const float* __restrict__ Qs,
                 const float* __restrict__ Kc, const float* __restrict__ Ks,
                 const float* __restrict__ Vv, unsigned short* __restrict__ out)
{
    __shared__ float sQc[QB][HDIM + 4];
    __shared__ float sQs[QB][HDIM + 4];
    __shared__ float sKc[MB][65];
    __shared__ float sKs[MB][65];
    __shared__ float sV [MB][68];
    __shared__ float sAre[QB][17];
    __shared__ float sAim[QB][17];
    __shared__ float gtab[WMAX];          // total ~49 KB

    const int tid = threadIdx.x;
    const int b   = blockIdx.x >> 7;      // 128 q-tiles per batch
    const int t   = blockIdx.x & 127;
    const int n0  = t * QB;
    const size_t base = (size_t)b * SEQ * HDIM;

    if (tid < WMAX) gtab[tid] = powf(GAMMA, (float)tid);

    // stage Q tile: 16 rows x 256 cols (fp32)
    for (int i = tid; i < QB * HDIM; i += 256) {
        const int r = i >> 8, h = i & 255;
        sQc[r][h] = Qc[base + (size_t)(n0 + r) * HDIM + h];
        sQs[r][h] = Qs[base + (size_t)(n0 + r) * HDIM + h];
    }

    const int qr   = tid >> 4;            // 0..15: q-row within tile
    const int mr   = tid & 15;            // att col within m-chunk
    const int lane = tid & 15;            // PV 4-col group

    float accRe[4][4] = {}, accIm[4][4] = {};

    const int mc_lo = (n0 >= WMAX) ? ((n0 - (WMAX - 1)) >> 4) : 0;
    const int mc_hi = (n0 + QB - 1) >> 4;

    for (int mc = mc_lo; mc <= mc_hi; ++mc) {
        const int m0 = mc << 4;
        float are = 0.f, aim = 0.f;

        // ---- att entry (qr, mr): dot over h in 4 chunks of 64 ----
        for (int hc = 0; hc < 4; ++hc) {
            __syncthreads();              // sK free (prev readers done)
            for (int i = tid; i < MB * 64; i += 256) {
                const int r = i >> 6, hh = i & 63;
                const size_t g = base + (size_t)(m0 + r) * HDIM + hc * 64 + hh;
                sKc[r][hh] = Kc[g];
                sKs[r][hh] = Ks[g];
            }
            __syncthreads();
            const int hb = hc * 64;
            #pragma unroll 4
            for (int hh = 0; hh < 64; ++hh) {
                const float kc = sKc[mr][hh], ks = sKs[mr][hh];
                const float qc = sQc[qr][hb + hh], qs = sQs[qr][hb + hh];
                are += qc * kc + qs * ks;
                aim += qs * kc - qc * ks;
            }
        }

        // ---- decay + causal mask -> LDS att tile ----
        {
            const int j = (n0 + qr) - (m0 + mr);
            const float w = (j >= 0 && j < WMAX) ? gtab[j] : 0.f;
            sAre[qr][mr] = are * w;       // prev PV readers done (trailing barrier)
            sAim[qr][mr] = aim * w;
        }

        // ---- out += att x V, h' in 4 chunks of 64 ----
        for (int hc = 0; hc < 4; ++hc) {
            __syncthreads();              // sV free; sA visible (hc=0)
            for (int i = tid; i < MB * 64; i += 256) {
                const int r = i >> 6, hh = i & 63;
                sV[r][hh] = Vv[base + (size_t)(m0 + r) * HDIM + hc * 64 + hh];
            }
            __syncthreads();
            #pragma unroll 4
            for (int m = 0; m < MB; ++m) {
                const float ar = sAre[qr][m], ai = sAim[qr][m];
                const float4 v = *(const float4*)&sV[m][lane * 4];
                accRe[hc][0] += ar * v.x; accRe[hc][1] += ar * v.y;
                accRe[hc][2] += ar * v.z; accRe[hc][3] += ar * v.w;
                accIm[hc][0] += ai * v.x; accIm[hc][1] += ai * v.y;
                accIm[hc][2] += ai * v.z; accIm[hc][3] += ai * v.w;
            }
        }
        __syncthreads();                  // PV reads done before next sA write
    }

    // ---- epilogue: interleaved pairs, [IM, RE] order ----
    const size_t orow = (size_t)b * SEQ + n0 + qr;
    #pragma unroll
    for (int hc = 0; hc < 4; ++hc) {
        const int col0 = hc * 64 + lane * 4;
        ushort8 w;
        w[0] = f2bf(accIm[hc][0]); w[1] = f2bf(accRe[hc][0]);
        w[2] = f2bf(accIm[hc][1]); w[3] = f2bf(accRe[hc][1]);
        w[4] = f2bf(accIm[hc][2]); w[5] = f2bf(accRe[hc][2]);
        w[6] = f2bf(accIm[hc][3]); w[7] = f2bf(accRe[hc][3]);
        *(ushort8*)&out[(orow * HDIM + col0) * 2] = w;   // 16B store
    }
}

// ---------------------------------------------------------------------------
extern "C" void kernel_launch(void* const* d_in, const int* in_sizes, int n_in,
                              void* d_out, int out_size, void* d_ws, size_t ws_size,
                              hipStream_t stream)
{
    const float* X     = (const float*)d_in[0];
    const float* WQ    = (const float*)d_in[1];
    const float* WK    = (const float*)d_in[2];
    const float* WV    = (const float*)d_in[3];
    const float* theta = (const float*)d_in[4];

    float* ws = (float*)d_ws;
    const size_t NTOK = (size_t)BATCH * SEQ * HDIM;   // 2,097,152
    float* Qc = ws;
    float* Qs = Qc + NTOK;
    float* Kc = Qs + NTOK;
    float* Ks = Kc + NTOK;
    float* Vv = Ks + NTOK;                            // 40 MB total

    proj_kernel<<<dim3(BATCH * SEQ, 3), 256, 0, stream>>>(
        X, WQ, WK, WV, theta, Qc, Qs, Kc, Ks, Vv);

    attn_kernel<<<dim3(BATCH * (SEQ / QB)), 256, 0, stream>>>(
        Qc, Qs, Kc, Ks, Vv, (unsigned short*)d_out);
}

// Round 11
// 121.290 us; speedup vs baseline: 4.9272x; 4.9272x over previous
//
#include <hip/hip_runtime.h>
#include <math.h>

#define BATCH 4
#define SEQ   2048
#define HDIM  256
// log2(0.9): gamma^j = exp2(j*L2G). Window: 7 m-tiles (j<=223, tail ~1e-9)
#define L2G   -0.15200309344504995f

typedef __attribute__((ext_vector_type(8))) short short8;
typedef __attribute__((ext_vector_type(4))) float f32x4;

// Harness contract (established R1-R10): inputs fp32; d_out = bf16 view of
// complex64 (B,S,H), each element stored as [imag, real] bf16 pair.
__device__ __forceinline__ unsigned short f2bf(float f) {
    union { float f; unsigned int u; } v; v.f = f;
    unsigned int u = v.u;
    u += 0x7FFFu + ((u >> 16) & 1u);
    return (unsigned short)(u >> 16);
}
__device__ __forceinline__ float bf2f(short s) {
    union { unsigned int u; float f; } v;
    v.u = ((unsigned int)(unsigned short)s) << 16;
    return v.f;
}

// ---------------------------------------------------------------------------
// Kernel 0: W -> Wt[sec][col][k] bf16 (transposed so GEMM B-fragments are
// contiguous 16B per lane). 768 KB read once; coalesced 2B stores over k.
// ---------------------------------------------------------------------------
__global__ __launch_bounds__(256)
void prep_kernel(const float* __restrict__ WQ, const float* __restrict__ WK,
                 const float* __restrict__ WV, unsigned short* __restrict__ Wt)
{
    const int sec  = blockIdx.y;             // 0..2
    const int col0 = blockIdx.x * 16;        // 0..240
    const int k    = threadIdx.x;            // 0..255
    const float* W = (sec == 0) ? WQ : (sec == 1) ? WK : WV;
    #pragma unroll
    for (int c = 0; c < 16; ++c)
        Wt[((size_t)(sec * 256 + col0 + c)) * 256 + k] =
            f2bf(W[(size_t)k * 256 + col0 + c]);
}

// ---------------------------------------------------------------------------
// Kernel 1: proj — C = X @ W[sec] via MFMA. grid (3 sections, 128 row-tiles),
// 256 thr = 4 waves, each wave: 64 rows x 64 cols (4x4 16x16 fragments).
// A (X) staged once in fragment-order LDS; B loaded 16B/lane from Wt (L2).
// Outputs: Qb, Kb row-major bf16; V written TRANSPOSED: Vt[b][h][s].
// ---------------------------------------------------------------------------
__global__ __launch_bounds__(256, 1)
void proj_kernel(const float* __restrict__ X, const unsigned short* __restrict__ Wt,
                 unsigned short* __restrict__ Qb, unsigned short* __restrict__ Kb,
                 unsigned short* __restrict__ Vt)
{
    // frag-order blob: [kstep 8][mfrag 4][lane 64][8 bf16] = 32 KB
    __shared__ __align__(16) short sX[8][4][64][8];

    const int tid  = threadIdx.x;
    const int sec  = blockIdx.x;
    const int row0 = blockIdx.y * 64;

    // stage X tile (64 rows x 256 k) fp32 -> bf16 frag-order
    {
        const int row = tid >> 2, kq = (tid & 3) * 64;
        #pragma unroll
        for (int g = 0; g < 8; ++g) {
            const int k = kq + g * 8;
            const float* xp = &X[(size_t)(row0 + row) * 256 + k];
            const float4 xa = *(const float4*)xp;
            const float4 xb = *(const float4*)(xp + 4);
            short8 v;
            v[0] = (short)f2bf(xa.x); v[1] = (short)f2bf(xa.y);
            v[2] = (short)f2bf(xa.z); v[3] = (short)f2bf(xa.w);
            v[4] = (short)f2bf(xb.x); v[5] = (short)f2bf(xb.y);
            v[6] = (short)f2bf(xb.z); v[7] = (short)f2bf(xb.w);
            *(short8*)&sX[k >> 5][row >> 4][((k & 31) >> 3) * 16 + (row & 15)][0] = v;
        }
    }
    __syncthreads();

    const int wave = tid >> 6, l = tid & 63;
    const int lhi = l >> 4, l15 = l & 15;

    f32x4 acc[4][4] = {};
    #pragma unroll
    for (int ks = 0; ks < 8; ++ks) {
        short8 a[4], bf[4];
        #pragma unroll
        for (int mf = 0; mf < 4; ++mf)
            a[mf] = *(const short8*)&sX[ks][mf][l][0];
        #pragma unroll
        for (int nf = 0; nf < 4; ++nf)
            bf[nf] = *(const short8*)&Wt[((size_t)(sec * 256 + wave * 64 + nf * 16 + l15)) * 256
                                         + ks * 32 + lhi * 8];
        #pragma unroll
        for (int mf = 0; mf < 4; ++mf)
            #pragma unroll
            for (int nf = 0; nf < 4; ++nf)
                acc[mf][nf] = __builtin_amdgcn_mfma_f32_16x16x32_bf16(
                    a[mf], bf[nf], acc[mf][nf], 0, 0, 0);
    }

    // epilogue: direct bf16 stores (L2 merges the 32B runs)
    #pragma unroll
    for (int mf = 0; mf < 4; ++mf)
        #pragma unroll
        for (int nf = 0; nf < 4; ++nf)
            #pragma unroll
            for (int r = 0; r < 4; ++r) {
                const int row = row0 + mf * 16 + lhi * 4 + r;
                const int col = wave * 64 + nf * 16 + l15;
                const unsigned short v = f2bf(acc[mf][nf][r]);
                if (sec == 0)      Qb[(size_t)row * 256 + col] = v;
                else if (sec == 1) Kb[(size_t)row * 256 + col] = v;
                else {
                    const int b = row >> 11, s = row & 2047;
                    Vt[((size_t)(b * 256 + col)) * 2048 + s] = v;
                }
            }
}

// ---------------------------------------------------------------------------
// Kernel 2: attn — banded complex retention via MFMA.
// Per block: 32 q-rows. Q rotated in-register; per m-tile: K rotated while
// staging, att = 4 GEMM combos (re=A+B, im=A-B), gamma^j decay in registers,
// PV accumulates fp32. Out: [im,re] bf16 pairs packed as u32.
// ---------------------------------------------------------------------------
__global__ __launch_bounds__(256, 1)
void attn_kernel(const unsigned short* __restrict__ Qb,
                 const unsigned short* __restrict__ Kb,
                 const unsigned short* __restrict__ Vt,
                 const float* __restrict__ theta,
                 unsigned int* __restrict__ out)
{
    __shared__ __align__(16) short sKc[8][2][64][8];   // 16 KB  [ks][mf][lane][8]
    __shared__ __align__(16) short sKs[8][2][64][8];   // 16 KB
    __shared__ __align__(16) short sVt[16][64][8];     // 16 KB  [hf][lane][8]
    __shared__ __align__(16) short sAtt[2][2][64][8];  //  4 KB  [re/im][nf][lane][8]

    const int tid = threadIdx.x;
    const int b   = blockIdx.x >> 6;
    const int qt  = blockIdx.x & 63;
    const int n0  = qt * 32;
    const int bS  = b * 2048;

    const int wave = tid >> 6, l = tid & 63;
    const int wn = wave >> 1, wm = wave & 1;
    const int lhi = l >> 4, l15 = l & 15;

    // ---- Q fragments, rotated in-register ----
    short8 qc[8], qs[8];
    {
        const int nq = n0 + wn * 16 + l15;
        const float nf1 = (float)(nq + 1);
        #pragma unroll
        for (int ks = 0; ks < 8; ++ks) {
            const short8 q8 = *(const short8*)&Qb[(size_t)(bS + nq) * 256 + ks * 32 + lhi * 8];
            const float* tp = &theta[ks * 32 + lhi * 8];
            short8 c8, s8;
            #pragma unroll
            for (int j = 0; j < 8; ++j) {
                const float a = nf1 * tp[j];
                const float sn = __sinf(a), cs = __cosf(a);
                const float qf = bf2f(q8[j]);
                c8[j] = (short)f2bf(qf * cs);
                s8[j] = (short)f2bf(qf * sn);
            }
            qc[ks] = c8; qs[ks] = s8;
        }
    }

    f32x4 oRe[8] = {}, oIm[8] = {};

    const int mt_lo = (qt >= 6) ? qt - 6 : 0;
    for (int mt = mt_lo; mt <= qt; ++mt) {
        const int m0 = mt * 32;

        // ---- stage K (rotate on the fly) ----
        {
            const int m = tid >> 3, gm = m0 + m;
            const float mf1 = (float)(gm + 1);
            #pragma unroll
            for (int hg = 0; hg < 4; ++hg) {
                const int h = hg * 64 + (tid & 7) * 8;
                const short8 k8 = *(const short8*)&Kb[(size_t)(bS + gm) * 256 + h];
                const float* tp = &theta[h];
                short8 c8, s8;
                #pragma unroll
                for (int j = 0; j < 8; ++j) {
                    const float a = mf1 * tp[j];
                    const float sn = __sinf(a), cs = __cosf(a);
                    const float kf = bf2f(k8[j]);
                    c8[j] = (short)f2bf(kf * cs);
                    s8[j] = (short)f2bf(kf * sn);
                }
                const int ln = ((h & 31) >> 3) * 16 + (m & 15);
                *(short8*)&sKc[h >> 5][m >> 4][ln][0] = c8;
                *(short8*)&sKs[h >> 5][m >> 4][ln][0] = s8;
            }
        }
        // ---- stage V (already transposed in ws: contiguous per h-row) ----
        {
            const unsigned short* vp = &Vt[((size_t)(b * 256 + tid)) * 2048 + m0];
            #pragma unroll
            for (int mg = 0; mg < 4; ++mg)
                *(short8*)&sVt[tid >> 4][mg * 16 + (tid & 15)][0] =
                    *(const short8*)&vp[mg * 8];
        }
        __syncthreads();

        // ---- att: 4 acc chains for ILP; re = rA+rB, im = iA-iB ----
        f32x4 rA = {}, rB = {}, iA = {}, iB = {};
        #pragma unroll
        for (int ks = 0; ks < 8; ++ks) {
            const short8 kc = *(const short8*)&sKc[ks][wm][l][0];
            const short8 kg = *(const short8*)&sKs[ks][wm][l][0];
            rA = __builtin_amdgcn_mfma_f32_16x16x32_bf16(qc[ks], kc, rA, 0, 0, 0);
            rB = __builtin_amdgcn_mfma_f32_16x16x32_bf16(qs[ks], kg, rB, 0, 0, 0);
            iA = __builtin_amdgcn_mfma_f32_16x16x32_bf16(qs[ks], kc, iA, 0, 0, 0);
            iB = __builtin_amdgcn_mfma_f32_16x16x32_bf16(qc[ks], kg, iB, 0, 0, 0);
        }

        // ---- decay in registers -> bf16 att tile in LDS ----
        #pragma unroll
        for (int r = 0; r < 4; ++r) {
            const int n = n0 + wn * 16 + lhi * 4 + r;
            const int m = m0 + wm * 16 + l15;
            const int j = n - m;
            const float wgt = (j >= 0) ? __builtin_exp2f((float)j * L2G) : 0.f;
            const int lidx = (wm * 2 + (l15 >> 3)) * 16 + lhi * 4 + r;
            sAtt[0][wn][lidx][l15 & 7] = (short)f2bf((rA[r] + rB[r]) * wgt);
            sAtt[1][wn][lidx][l15 & 7] = (short)f2bf((iA[r] - iB[r]) * wgt);
        }
        __syncthreads();

        // ---- PV: out += att x V ----
        const short8 aRe = *(const short8*)&sAtt[0][wn][l][0];
        const short8 aIm = *(const short8*)&sAtt[1][wn][l][0];
        #pragma unroll
        for (int f = 0; f < 8; ++f) {
            const short8 vf = *(const short8*)&sVt[wm * 8 + f][l][0];
            oRe[f] = __builtin_amdgcn_mfma_f32_16x16x32_bf16(aRe, vf, oRe[f], 0, 0, 0);
            oIm[f] = __builtin_amdgcn_mfma_f32_16x16x32_bf16(aIm, vf, oIm[f], 0, 0, 0);
        }
        __syncthreads();   // protect sK/sVt/sAtt overwrite next iteration
    }

    // ---- output: [im, re] bf16 pairs as packed u32 ----
    #pragma unroll
    for (int f = 0; f < 8; ++f)
        #pragma unroll
        for (int r = 0; r < 4; ++r) {
            const int n  = n0 + wn * 16 + lhi * 4 + r;
            const int hp = wm * 128 + f * 16 + l15;
            const unsigned int re16 = f2bf(oRe[f][r]);
            const unsigned int im16 = f2bf(oIm[f][r]);
            out[(size_t)(bS + n) * 256 + hp] = (re16 << 16) | im16;
        }
}

// ---------------------------------------------------------------------------
extern "C" void kernel_launch(void* const* d_in, const int* in_sizes, int n_in,
                              void* d_out, int out_size, void* d_ws, size_t ws_size,
                              hipStream_t stream)
{
    const float* X     = (const float*)d_in[0];
    const float* WQ    = (const float*)d_in[1];
    const float* WK    = (const float*)d_in[2];
    const float* WV    = (const float*)d_in[3];
    const float* theta = (const float*)d_in[4];

    // ws: Wt (384 KB) | Qb (4 MB) | Kb (4 MB) | Vt (4 MB)  — 12.4 MB (<40 MB proven)
    unsigned short* Wt = (unsigned short*)d_ws;
    unsigned short* Qb = Wt + (size_t)3 * 256 * 256;
    unsigned short* Kb = Qb + (size_t)BATCH * SEQ * HDIM;
    unsigned short* Vt = Kb + (size_t)BATCH * SEQ * HDIM;

    prep_kernel<<<dim3(16, 3), 256, 0, stream>>>(WQ, WK, WV, Wt);
    proj_kernel<<<dim3(3, 128), 256, 0, stream>>>(X, Wt, Qb, Kb, Vt);
    attn_kernel<<<dim3(BATCH * (SEQ / 32)), 256, 0, stream>>>(
        Qb, Kb, Vt, theta, (unsigned int*)d_out);
}

// Round 12
// 114.252 us; speedup vs baseline: 5.2307x; 1.0616x over previous
//
#include <hip/hip_runtime.h>
#include <math.h>

#define BATCH 4
#define SEQ   2048
#define HDIM  256
// log2(0.9): gamma^j = exp2(j*L2G). Window: 7 m-tiles (j<=223, tail ~1e-9)
#define L2G   -0.15200309344504995f

typedef __attribute__((ext_vector_type(8))) short short8;
typedef __attribute__((ext_vector_type(4))) float f32x4;

// Harness contract (established R1-R10): inputs fp32; d_out = bf16 view of
// complex64 (B,S,H), each element stored as [imag, real] bf16 pair.
__device__ __forceinline__ unsigned short f2bf(float f) {
    union { float f; unsigned int u; } v; v.f = f;
    unsigned int u = v.u;
    u += 0x7FFFu + ((u >> 16) & 1u);
    return (unsigned short)(u >> 16);
}

// ---------------------------------------------------------------------------
// Kernel 0: W -> Wt[sec][col][k] bf16 (transposed so GEMM B-fragments are
// contiguous 16B per lane).
// ---------------------------------------------------------------------------
__global__ __launch_bounds__(256)
void prep_kernel(const float* __restrict__ WQ, const float* __restrict__ WK,
                 const float* __restrict__ WV, unsigned short* __restrict__ Wt)
{
    const int sec  = blockIdx.y;             // 0..2
    const int col0 = blockIdx.x * 16;        // 0..240
    const int k    = threadIdx.x;            // 0..255
    const float* W = (sec == 0) ? WQ : (sec == 1) ? WK : WV;
    #pragma unroll
    for (int c = 0; c < 16; ++c)
        Wt[((size_t)(sec * 256 + col0 + c)) * 256 + k] =
            f2bf(W[(size_t)k * 256 + col0 + c]);
}

// ---------------------------------------------------------------------------
// Kernel 1: fused proj — Q,K,V = X @ {WQ,WK,WV} via MFMA, ROTATION IN
// EPILOGUE (fp32 acc rotated before the single bf16 cast).
// grid 256 blocks (32 rows each); X staged once, A-frags held in registers
// across the 3 sections. Outputs: Qc,Qs,Kc,Ks row-major bf16; Vt[b][h][s].
// ---------------------------------------------------------------------------
__global__ __launch_bounds__(256, 1)
void proj_kernel(const float* __restrict__ X, const unsigned short* __restrict__ Wt,
                 const float* __restrict__ theta,
                 unsigned short* __restrict__ Qc, unsigned short* __restrict__ Qs,
                 unsigned short* __restrict__ Kc, unsigned short* __restrict__ Ks,
                 unsigned short* __restrict__ Vt)
{
    __shared__ __align__(16) short sX[8][2][64][8];   // 16 KB frag-order

    const int tid  = threadIdx.x;
    const int row0 = blockIdx.x * 32;

    // stage X tile (32 rows x 256 k) fp32 -> bf16 frag-order
    {
        const int row = tid >> 3, kq = (tid & 7) * 32;
        #pragma unroll
        for (int g = 0; g < 4; ++g) {
            const int k = kq + g * 8;
            const float* xp = &X[(size_t)(row0 + row) * 256 + k];
            const float4 xa = *(const float4*)xp;
            const float4 xb = *(const float4*)(xp + 4);
            short8 v;
            v[0] = (short)f2bf(xa.x); v[1] = (short)f2bf(xa.y);
            v[2] = (short)f2bf(xa.z); v[3] = (short)f2bf(xa.w);
            v[4] = (short)f2bf(xb.x); v[5] = (short)f2bf(xb.y);
            v[6] = (short)f2bf(xb.z); v[7] = (short)f2bf(xb.w);
            *(short8*)&sX[k >> 5][row >> 4][((k & 31) >> 3) * 16 + (row & 15)][0] = v;
        }
    }
    __syncthreads();

    const int wave = tid >> 6, l = tid & 63;
    const int lhi = l >> 4, l15 = l & 15;

    // A fragments in registers, reused for all 3 sections
    short8 a[8][2];
    #pragma unroll
    for (int ks = 0; ks < 8; ++ks)
        #pragma unroll
        for (int mf = 0; mf < 2; ++mf)
            a[ks][mf] = *(const short8*)&sX[ks][mf][l][0];

    float th[4];
    #pragma unroll
    for (int nf = 0; nf < 4; ++nf)
        th[nf] = theta[wave * 64 + nf * 16 + l15];

    #pragma unroll
    for (int sec = 0; sec < 3; ++sec) {
        f32x4 acc[2][4] = {};
        #pragma unroll
        for (int ks = 0; ks < 8; ++ks) {
            short8 bf[4];
            #pragma unroll
            for (int nf = 0; nf < 4; ++nf)
                bf[nf] = *(const short8*)&Wt[((size_t)(sec * 256 + wave * 64 + nf * 16 + l15)) * 256
                                             + ks * 32 + lhi * 8];
            #pragma unroll
            for (int mf = 0; mf < 2; ++mf)
                #pragma unroll
                for (int nf = 0; nf < 4; ++nf)
                    acc[mf][nf] = __builtin_amdgcn_mfma_f32_16x16x32_bf16(
                        a[ks][mf], bf[nf], acc[mf][nf], 0, 0, 0);
        }

        if (sec < 2) {
            unsigned short* Pc = sec ? Kc : Qc;
            unsigned short* Ps = sec ? Ks : Qs;
            #pragma unroll
            for (int mf = 0; mf < 2; ++mf)
                #pragma unroll
                for (int r = 0; r < 4; ++r) {
                    const int row = row0 + mf * 16 + lhi * 4 + r;
                    const float sf = (float)((row & (SEQ - 1)) + 1);
                    #pragma unroll
                    for (int nf = 0; nf < 4; ++nf) {
                        const int col = wave * 64 + nf * 16 + l15;
                        const float ang = sf * th[nf];
                        const float sn = __sinf(ang), cs = __cosf(ang);
                        const float v = acc[mf][nf][r];
                        Pc[(size_t)row * 256 + col] = f2bf(v * cs);
                        Ps[(size_t)row * 256 + col] = f2bf(v * sn);
                    }
                }
        } else {
            #pragma unroll
            for (int mf = 0; mf < 2; ++mf)
                #pragma unroll
                for (int nf = 0; nf < 4; ++nf)
                    #pragma unroll
                    for (int r = 0; r < 4; ++r) {
                        const int row = row0 + mf * 16 + lhi * 4 + r;
                        const int col = wave * 64 + nf * 16 + l15;
                        const int b = row >> 11, s = row & (SEQ - 1);
                        Vt[((size_t)(b * 256 + col)) * 2048 + s] = f2bf(acc[mf][nf][r]);
                    }
        }
    }
}

// ---------------------------------------------------------------------------
// Kernel 2: attn — banded complex retention, pure stage+MFMA (no rotation).
// Per block: 32 q-rows; 7 m-tiles; QK = 4 GEMM combos; gamma^j in registers;
// PV accumulates fp32. Out: [im,re] bf16 pairs packed as u32.
// ---------------------------------------------------------------------------
__global__ __launch_bounds__(256, 1)
void attn_kernel(const unsigned short* __restrict__ Qc,
                 const unsigned short* __restrict__ Qs,
                 const unsigned short* __restrict__ Kc,
                 const unsigned short* __restrict__ Ks,
                 const unsigned short* __restrict__ Vt,
                 unsigned int* __restrict__ out)
{
    __shared__ __align__(16) short sKc[8][2][64][8];   // 16 KB
    __shared__ __align__(16) short sKs[8][2][64][8];   // 16 KB
    __shared__ __align__(16) short sVt[16][64][8];     // 16 KB
    __shared__ __align__(16) short sAtt[2][2][64][8];  //  4 KB

    const int tid = threadIdx.x;
    const int b   = blockIdx.x >> 6;
    const int qt  = blockIdx.x & 63;
    const int n0  = qt * 32;
    const int bS  = b * 2048;

    const int wave = tid >> 6, l = tid & 63;
    const int wn = wave >> 1, wm = wave & 1;
    const int lhi = l >> 4, l15 = l & 15;

    // ---- Q fragments: pre-rotated, straight loads ----
    short8 qc[8], qs[8];
    {
        const int nq = n0 + wn * 16 + l15;
        #pragma unroll
        for (int ks = 0; ks < 8; ++ks) {
            const size_t o = (size_t)(bS + nq) * 256 + ks * 32 + lhi * 8;
            qc[ks] = *(const short8*)&Qc[o];
            qs[ks] = *(const short8*)&Qs[o];
        }
    }

    f32x4 oRe[8] = {}, oIm[8] = {};

    const int mt_lo = (qt >= 6) ? qt - 6 : 0;
    for (int mt = mt_lo; mt <= qt; ++mt) {
        const int m0 = mt * 32;

        // ---- stage K (pure copy into frag-order LDS) ----
        {
            const int m = tid >> 3, gm = m0 + m;
            const size_t rb = (size_t)(bS + gm) * 256;
            #pragma unroll
            for (int hg = 0; hg < 4; ++hg) {
                const int h = hg * 64 + (tid & 7) * 8;
                const short8 c8 = *(const short8*)&Kc[rb + h];
                const short8 s8 = *(const short8*)&Ks[rb + h];
                const int ln = ((h & 31) >> 3) * 16 + (m & 15);
                *(short8*)&sKc[h >> 5][m >> 4][ln][0] = c8;
                *(short8*)&sKs[h >> 5][m >> 4][ln][0] = s8;
            }
        }
        // ---- stage V ----
        {
            const unsigned short* vp = &Vt[((size_t)(b * 256 + tid)) * 2048 + m0];
            #pragma unroll
            for (int mg = 0; mg < 4; ++mg)
                *(short8*)&sVt[tid >> 4][mg * 16 + (tid & 15)][0] =
                    *(const short8*)&vp[mg * 8];
        }
        __syncthreads();

        // ---- att: 4 acc chains; re = rA+rB, im = iA-iB ----
        f32x4 rA = {}, rB = {}, iA = {}, iB = {};
        #pragma unroll
        for (int ks = 0; ks < 8; ++ks) {
            const short8 kc = *(const short8*)&sKc[ks][wm][l][0];
            const short8 kg = *(const short8*)&sKs[ks][wm][l][0];
            rA = __builtin_amdgcn_mfma_f32_16x16x32_bf16(qc[ks], kc, rA, 0, 0, 0);
            rB = __builtin_amdgcn_mfma_f32_16x16x32_bf16(qs[ks], kg, rB, 0, 0, 0);
            iA = __builtin_amdgcn_mfma_f32_16x16x32_bf16(qs[ks], kc, iA, 0, 0, 0);
            iB = __builtin_amdgcn_mfma_f32_16x16x32_bf16(qc[ks], kg, iB, 0, 0, 0);
        }

        // ---- decay in registers -> bf16 att tile in LDS ----
        #pragma unroll
        for (int r = 0; r < 4; ++r) {
            const int n = n0 + wn * 16 + lhi * 4 + r;
            const int m = m0 + wm * 16 + l15;
            const int j = n - m;
            const float wgt = (j >= 0) ? __builtin_exp2f((float)j * L2G) : 0.f;
            const int lidx = (wm * 2 + (l15 >> 3)) * 16 + lhi * 4 + r;
            sAtt[0][wn][lidx][l15 & 7] = (short)f2bf((rA[r] + rB[r]) * wgt);
            sAtt[1][wn][lidx][l15 & 7] = (short)f2bf((iA[r] - iB[r]) * wgt);
        }
        __syncthreads();

        // ---- PV: out += att x V ----
        const short8 aRe = *(const short8*)&sAtt[0][wn][l][0];
        const short8 aIm = *(const short8*)&sAtt[1][wn][l][0];
        #pragma unroll
        for (int f = 0; f < 8; ++f) {
            const short8 vf = *(const short8*)&sVt[wm * 8 + f][l][0];
            oRe[f] = __builtin_amdgcn_mfma_f32_16x16x32_bf16(aRe, vf, oRe[f], 0, 0, 0);
            oIm[f] = __builtin_amdgcn_mfma_f32_16x16x32_bf16(aIm, vf, oIm[f], 0, 0, 0);
        }
        __syncthreads();   // protect sK/sVt/sAtt overwrite next iteration
    }

    // ---- output: [im, re] bf16 pairs as packed u32 ----
    #pragma unroll
    for (int f = 0; f < 8; ++f)
        #pragma unroll
        for (int r = 0; r < 4; ++r) {
            const int n  = n0 + wn * 16 + lhi * 4 + r;
            const int hp = wm * 128 + f * 16 + l15;
            const unsigned int re16 = f2bf(oRe[f][r]);
            const unsigned int im16 = f2bf(oIm[f][r]);
            out[(size_t)(bS + n) * 256 + hp] = (re16 << 16) | im16;
        }
}

// ---------------------------------------------------------------------------
extern "C" void kernel_launch(void* const* d_in, const int* in_sizes, int n_in,
                              void* d_out, int out_size, void* d_ws, size_t ws_size,
                              hipStream_t stream)
{
    const float* X     = (const float*)d_in[0];
    const float* WQ    = (const float*)d_in[1];
    const float* WK    = (const float*)d_in[2];
    const float* WV    = (const float*)d_in[3];
    const float* theta = (const float*)d_in[4];

    // ws: Wt 384KB | Qc,Qs,Kc,Ks 4MB each | Vt 4MB  = ~20.4 MB
    unsigned short* Wt = (unsigned short*)d_ws;
    unsigned short* Qc = Wt + (size_t)3 * 256 * 256;
    unsigned short* Qs = Qc + (size_t)BATCH * SEQ * HDIM;
    unsigned short* Kc = Qs + (size_t)BATCH * SEQ * HDIM;
    unsigned short* Ks = Kc + (size_t)BATCH * SEQ * HDIM;
    unsigned short* Vt = Ks + (size_t)BATCH * SEQ * HDIM;

    prep_kernel<<<dim3(16, 3), 256, 0, stream>>>(WQ, WK, WV, Wt);
    proj_kernel<<<dim3(256), 256, 0, stream>>>(X, Wt, theta, Qc, Qs, Kc, Ks, Vt);
    attn_kernel<<<dim3(BATCH * (SEQ / 32)), 256, 0, stream>>>(
        Qc, Qs, Kc, Ks, Vt, (unsigned int*)d_out);
}